// Round 7
// baseline (117.312 us; speedup 1.0000x reference)
//
#include <hip/hip_runtime.h>

typedef float f4 __attribute__((ext_vector_type(4)));

constexpr int N_  = 4;
constexpr int C_  = 320;
constexpr int H_  = 80;
constexpr int W_  = 160;
constexpr int G_  = 40;
constexpr int CPG = 8;                   // channels per group
constexpr int D_  = 48;                  // max disparity
constexpr int HW  = H_ * W_;             // channel stride (floats)
constexpr int QW  = 40;                  // quarter-row width per wave-task
constexpr int NQ  = W_ / QW;             // 4 quarter tasks per row
constexpr int PADW = 48;                 // R window left extension
constexpr int RWN  = PADW + QW;          // 88-float R window per channel
constexpr int TPW  = (QW / 4) * (D_ / 4);// 120 4w x 4d tiles per task

__global__ __launch_bounds__(256) void gw_cost_kernel(const float* __restrict__ Lg,
                                                      const float* __restrict__ Rg,
                                                      float* __restrict__ out) {
    // Per-wave private LDS slices: no inter-wave sharing, no __syncthreads.
    __shared__ float Ls[4][CPG][QW];    // 4 x 1280 B
    __shared__ float Rs[4][CPG][RWN];   // 4 x 2816 B   (16 KB total -> 8 blocks/CU)

    const int tid  = threadIdx.x;
    const int wid  = tid >> 6;
    const int lane = tid & 63;

    const int task = blockIdx.x * 4 + wid;   // 51200 wave-tasks
    const int q    = task & (NQ - 1);
    const int row  = task >> 2;              // ((n*G + g)*H + h)
    const int h = row % H_;
    const int g = (row / H_) % G_;
    const int n = row / (H_ * G_);
    const int w0q = q * QW;

    const size_t base = (size_t)(n * C_ + g * CPG) * HW + (size_t)h * W_;

    // Window covers global R indices [w0q-48, w0q+40); indices <0 are zeros.
    const int zl = (q == 0) ? PADW : (q == 1 ? 8 : 0);   // zero floats at window start

    // zero the pad region [0, zl) for all channels (lanes 0..zl/4-1)
    if (lane * 4 < zl) {
        #pragma unroll
        for (int c = 0; c < CPG; ++c)
            *(f4*)&Rs[wid][c][lane * 4] = (f4)(0.0f);
    }

    // ---- DMA global -> this wave's LDS slice (wave-uniform dest base + lane*16) ----
    const int goffR = w0q - PADW + zl;       // >= 0, multiple of 4
    const int nlR   = (RWN - zl) / 4;        // active lanes for R DMA (10/20/22/22)
    #pragma unroll
    for (int c = 0; c < CPG; ++c) {
        if (lane < QW / 4) {
            const float* gl = Lg + base + (size_t)c * HW + w0q + lane * 4;
            __builtin_amdgcn_global_load_lds(
                (const __attribute__((address_space(1))) void*)gl,
                (__attribute__((address_space(3))) void*)&Ls[wid][c][0], 16, 0, 0);
        }
        if (lane < nlR) {
            const float* gr = Rg + base + (size_t)c * HW + goffR + lane * 4;
            __builtin_amdgcn_global_load_lds(
                (const __attribute__((address_space(1))) void*)gr,
                (__attribute__((address_space(3))) void*)&Rs[wid][c][zl], 16, 0, 0);
        }
    }
    // Wave-local wait for the DMA; memory clobber orders the ds_reads below.
    asm volatile("s_waitcnt vmcnt(0)" ::: "memory");
    __builtin_amdgcn_sched_barrier(0);
    // zero ds_writes -> ds_reads ordering is tracked by the compiler via lgkmcnt.

    // ---- compute: proven 4w x 4d core over this wave's 40x48 output patch ----
    for (int t = lane; t < TPW; t += 64) {
        const int twl = t / 12;
        const int td  = t % 12;
        const int w0l = twl * 4;
        const int d0  = td * 4;
        const int r0  = w0l - d0 + PADW;   // [4, 84]; reads r0-4 .. r0+3 within [0, 87]

        f4 a0 = (f4)(0.0f), a1 = (f4)(0.0f), a2 = (f4)(0.0f), a3 = (f4)(0.0f);

        #pragma unroll
        for (int c = 0; c < CPG; ++c) {
            const f4 lv = *(const f4*)&Ls[wid][c][w0l];
            const float* rp = &Rs[wid][c][r0 - 4];   // 16B-aligned
            const f4 ra = *(const f4*)(rp);
            const f4 rb = *(const f4*)(rp + 4);
            float rr[8];
            #pragma unroll
            for (int k = 0; k < 4; ++k) { rr[k] = ra[k]; rr[4 + k] = rb[k]; }
            // out(w0l+i, d0+j) += L[w0l+i] * Rlocal[r0 + i - j] -> rr[4 + i - j]
            #pragma unroll
            for (int j = 0; j < 4; ++j) {
                a0[j] += lv[0] * rr[4 + 0 - j];
                a1[j] += lv[1] * rr[4 + 1 - j];
                a2[j] += lv[2] * rr[4 + 2 - j];
                a3[j] += lv[3] * rr[4 + 3 - j];
            }
        }

        float* op = out + (size_t)row * (W_ * D_) + (size_t)(w0q + w0l) * D_ + d0;
        *(f4*)(op + 0 * D_) = a0 * 0.125f;
        *(f4*)(op + 1 * D_) = a1 * 0.125f;
        *(f4*)(op + 2 * D_) = a2 * 0.125f;
        *(f4*)(op + 3 * D_) = a3 * 0.125f;
    }
}

extern "C" void kernel_launch(void* const* d_in, const int* in_sizes, int n_in,
                              void* d_out, int out_size, void* d_ws, size_t ws_size,
                              hipStream_t stream) {
    const float* Lg = (const float*)d_in[0];
    const float* Rg = (const float*)d_in[1];
    float* out = (float*)d_out;

    const int nblocks = (N_ * G_ * H_ * NQ) / 4;   // 12800 blocks x 4 independent wave-tasks
    gw_cost_kernel<<<dim3(nblocks), dim3(256), 0, stream>>>(Lg, Rg, out);
}

// Round 8
// 116.374 us; speedup vs baseline: 1.0081x; 1.0081x over previous
//
#include <hip/hip_runtime.h>

typedef float f4 __attribute__((ext_vector_type(4)));

constexpr int N_  = 4;
constexpr int C_  = 320;
constexpr int H_  = 80;
constexpr int W_  = 160;
constexpr int G_  = 40;
constexpr int CPG = 8;                    // channels per group
constexpr int D_  = 48;                   // max disparity
constexpr int HW  = H_ * W_;              // channel stride (floats)
constexpr int ROWS   = N_ * G_ * H_;      // 12800 (n,g,h) rows
constexpr int CHUNKS = ROWS * 2;          // 25600 half-row chunks
constexpr int NBLK   = 2048;              // persistent blocks = 8 per CU
constexpr int HALF   = 80;                // w extent per chunk
constexpr int TPC    = (HALF / 4) * (D_ / 4);   // 240 4w x 4d tiles per chunk

__global__ __launch_bounds__(256) void gw_cost_kernel(const float* __restrict__ Lg,
                                                      const float* __restrict__ Rg,
                                                      float* __restrict__ out) {
    // double-buffered half-row stage: 2 x (8x80 L + 8x128 R) = 13312 B -> 8 blocks/CU
    __shared__ float Lsh[2][CPG][HALF];
    __shared__ float Rsh[2][CPG][128];   // float k <-> global w = k + par*80 - 48

    const int tid  = threadIdx.x;
    const int wid  = tid >> 6;
    const int lane = tid & 63;
    const int bid  = blockIdx.x;
    const int par  = bid & 1;            // fixed w-half parity for this block
    const int c0   = wid * 2;            // this wave stages channels c0, c0+1

    // par==0 blocks: window floats [0,48) per channel are permanent zeros (both buffers)
    if (par == 0 && tid < 2 * CPG * 12) {
        const int b = tid / 96, q = tid % 96, c = q / 12, p = q % 12;
        *(f4*)&Rsh[b][c][p * 4] = (f4)(0.0f);
    }

    const int roff = par ? 0 : 48;       // LDS float offset of first staged R element
    const int gw0  = par ? 32 : 0;       // global w of first staged R element
    const int nlR  = par ? 32 : 20;      // active lanes per R-channel DMA

    const int nch = (CHUNKS - bid + NBLK - 1) / NBLK;   // 12 or 13 chunks

    // fixed per-thread tile coords (valid for tid < TPC)
    const int w0l = (tid / 12) * 4;
    const int d0  = (tid % 12) * 4;
    const int r0l = w0l - d0 + 48;       // [4,124]; reads r0l-4 .. r0l+3 within [0,127]

    auto issue = [&](int k) {            // stage local chunk #k into buffer k&1
        const int ch = bid + k * NBLK;
        const int r  = ch >> 1;
        const size_t base = (size_t)(r / H_) * (CPG * HW) + (size_t)(r % H_) * W_;
        if (lane < 40) {                 // L: 2 channels x 320B, contiguous LDS dest
            const int cc = c0 + lane / 20, wq = (lane % 20) * 4;
            const float* s = Lg + base + (size_t)cc * HW + par * HALF + wq;
            __builtin_amdgcn_global_load_lds(
                (const __attribute__((address_space(1))) void*)s,
                (__attribute__((address_space(3))) void*)&Lsh[k & 1][c0][0], 16, 0, 0);
        }
        if (lane < nlR) {                // R: per-channel DMA (pad region untouched)
            const float* s0 = Rg + base + (size_t)c0 * HW + gw0 + lane * 4;
            __builtin_amdgcn_global_load_lds(
                (const __attribute__((address_space(1))) void*)s0,
                (__attribute__((address_space(3))) void*)&Rsh[k & 1][c0][roff], 16, 0, 0);
            const float* s1 = Rg + base + (size_t)(c0 + 1) * HW + gw0 + lane * 4;
            __builtin_amdgcn_global_load_lds(
                (const __attribute__((address_space(1))) void*)s1,
                (__attribute__((address_space(3))) void*)&Rsh[k & 1][c0 + 1][roff], 16, 0, 0);
        }
    };

    issue(0);
    asm volatile("s_waitcnt vmcnt(0)" ::: "memory");

    for (int k = 0; k < nch; ++k) {
        // my chunk-k loads done (in-order vmcnt: <=4 remaining are the newest 4 = my
        // previous-chunk stores, which may keep flying). lgkmcnt(0): my LDS reads/writes done.
        asm volatile("s_waitcnt vmcnt(4) lgkmcnt(0)" ::: "memory");
        __builtin_amdgcn_s_barrier();            // all waves: chunk-k data in LDS,
        __builtin_amdgcn_sched_barrier(0);       // prev chunk's readers finished

        if (k + 1 < nch) issue(k + 1);           // prefetch hides under compute below

        const int ch = bid + k * NBLK;
        const int r  = ch >> 1;
        const float (*Lp)[HALF] = Lsh[k & 1];
        const float (*Rp)[128]  = Rsh[k & 1];

        if (tid < TPC) {
            f4 a0 = (f4)(0.f), a1 = (f4)(0.f), a2 = (f4)(0.f), a3 = (f4)(0.f);
            #pragma unroll
            for (int c = 0; c < CPG; ++c) {
                const f4 lv = *(const f4*)&Lp[c][w0l];
                const float* rp = &Rp[c][r0l - 4];     // 16B-aligned
                const f4 ra = *(const f4*)rp;
                const f4 rb = *(const f4*)(rp + 4);
                float rr[8];
                #pragma unroll
                for (int t = 0; t < 4; ++t) { rr[t] = ra[t]; rr[4 + t] = rb[t]; }
                // out(w0l+i, d0+j) += L[w0l+i] * Rwin[r0l + i - j] -> rr[4 + i - j]
                #pragma unroll
                for (int j = 0; j < 4; ++j) {
                    a0[j] += lv[0] * rr[4 + 0 - j];
                    a1[j] += lv[1] * rr[4 + 1 - j];
                    a2[j] += lv[2] * rr[4 + 2 - j];
                    a3[j] += lv[3] * rr[4 + 3 - j];
                }
            }
            float* op = out + (size_t)r * (W_ * D_)
                        + (size_t)(par * HALF + w0l) * D_ + d0;
            *(f4*)(op + 0 * D_) = a0 * 0.125f;     // exactly 4 store instructions:
            *(f4*)(op + 1 * D_) = a1 * 0.125f;     // the vmcnt(4) contract above
            *(f4*)(op + 2 * D_) = a2 * 0.125f;
            *(f4*)(op + 3 * D_) = a3 * 0.125f;
        }
    }
}

extern "C" void kernel_launch(void* const* d_in, const int* in_sizes, int n_in,
                              void* d_out, int out_size, void* d_ws, size_t ws_size,
                              hipStream_t stream) {
    const float* Lg = (const float*)d_in[0];
    const float* Rg = (const float*)d_in[1];
    float* out = (float*)d_out;

    gw_cost_kernel<<<dim3(NBLK), dim3(256), 0, stream>>>(Lg, Rg, out);
}